// Round 3
// baseline (851.315 us; speedup 1.0000x reference)
//
#include <hip/hip_runtime.h>

// SpikeLinear: out = LIF_scan( x @ W^T + bias ) over T=8 timesteps.
//
// Numerics: the spike comparison (memb > 1.0) is discontinuous, so we must
// reproduce the harness's numpy fp32 reference bit-for-bit on the GEMM.
// numpy's float32 np.dot -> OpenBLAS sgemm accumulates each C element as a
// strict sequential fp32 FMA chain over ascending k, blocked by kc=384:
// per-panel register accumulation from zero, then C += panel (fp32 add).
// We replicate exactly that: fmaf chain per kc-panel, fp32 fold at panel
// boundaries (k = 384,768,...,3840), fp32 bias add, fp32 LIF scan.

constexpr int TSTEPS = 8;
constexpr int BK     = 16;
constexpr int TILE_M = 64;    // 8 batch rows * 8 timesteps
constexpr int TILE_N = 128;   // output columns per block
constexpr int KC     = 384;   // OpenBLAS SGEMM_DEFAULT_Q on x86-64

__global__ __launch_bounds__(256, 4)
void spike_linear_f32seq(const float* __restrict__ x,
                         const float* __restrict__ w,
                         const float* __restrict__ bias,
                         float* __restrict__ out,
                         int B, int IN, int OUT)
{
    // k-major LDS tiles. +4 pad keeps rows 16B-aligned (68*4=272B, 132*4=528B)
    // and rotates banks by 4 per k row.
    __shared__ float xs[BK][TILE_M + 4];
    __shared__ float ws[BK][TILE_N + 4];

    const int tid = threadIdx.x;
    const int tx  = tid & 31;    // column group: 4 consecutive outputs
    const int ty  = tid >> 5;    // batch row within tile (owns all 8 t)

    const int m0 = blockIdx.y * TILE_M;
    const int n0 = blockIdx.x * TILE_N;

    float acc_tot[TSTEPS][4];    // C memory value (panel sums folded in)
    float acc_blk[TSTEPS][4];    // current kc-panel register accumulator
    #pragma unroll
    for (int t = 0; t < TSTEPS; ++t)
        #pragma unroll
        for (int c = 0; c < 4; ++c) { acc_tot[t][c] = 0.f; acc_blk[t][c] = 0.f; }

    // staging: thread -> (row sr, k-offset sk); one float4 of x, two of w
    const int sr = tid >> 2;         // 0..63
    const int sk = (tid & 3) * 4;    // 0,4,8,12

    const float* xrow  = x + (size_t)(m0 + sr) * IN + sk;
    const float* wrow0 = w + (size_t)(n0 + sr) * IN + sk;
    const float* wrow1 = w + (size_t)(n0 + 64 + sr) * IN + sk;

    for (int kk = 0; kk < IN; kk += BK) {
        // kc-panel boundary: fold panel into C exactly like BLAS (C += panel)
        if (kk > 0 && (kk % KC) == 0) {
            #pragma unroll
            for (int t = 0; t < TSTEPS; ++t)
                #pragma unroll
                for (int c = 0; c < 4; ++c) {
                    acc_tot[t][c] += acc_blk[t][c];
                    acc_blk[t][c] = 0.f;
                }
        }

        const float4 xv  = *(const float4*)(xrow  + kk);
        const float4 wv0 = *(const float4*)(wrow0 + kk);
        const float4 wv1 = *(const float4*)(wrow1 + kk);
        __syncthreads();
        xs[sk+0][sr] = xv.x;  xs[sk+1][sr] = xv.y;
        xs[sk+2][sr] = xv.z;  xs[sk+3][sr] = xv.w;
        ws[sk+0][sr] = wv0.x; ws[sk+1][sr] = wv0.y;
        ws[sk+2][sr] = wv0.z; ws[sk+3][sr] = wv0.w;
        ws[sk+0][sr+64] = wv1.x; ws[sk+1][sr+64] = wv1.y;
        ws[sk+2][sr+64] = wv1.z; ws[sk+3][sr+64] = wv1.w;
        __syncthreads();

        #pragma unroll
        for (int k = 0; k < BK; ++k) {
            float xr[TSTEPS];
            *(float4*)&xr[0] = *(const float4*)&xs[k][ty*8];
            *(float4*)&xr[4] = *(const float4*)&xs[k][ty*8 + 4];
            float wr[4];
            *(float4*)&wr[0] = *(const float4*)&ws[k][tx*4];
            #pragma unroll
            for (int t = 0; t < TSTEPS; ++t)
                #pragma unroll
                for (int c = 0; c < 4; ++c)
                    acc_blk[t][c] = fmaf(xr[t], wr[c], acc_blk[t][c]);
        }
    }
    // final panel fold (last panel is 256 wide: 4096 = 10*384 + 256)
    #pragma unroll
    for (int t = 0; t < TSTEPS; ++t)
        #pragma unroll
        for (int c = 0; c < 4; ++c)
            acc_tot[t][c] += acc_blk[t][c];

    // epilogue: fp32 bias add (numpy order), fp32 LIF scan.
    const int bg = blockIdx.y * 8 + ty;   // global batch index
    const int o0 = n0 + tx * 4;
    const float4 bv = *(const float4*)(bias + o0);
    const float bb[4] = {bv.x, bv.y, bv.z, bv.w};
    float memb[4] = {0.f, 0.f, 0.f, 0.f};
    #pragma unroll
    for (int t = 0; t < TSTEPS; ++t) {
        float4 sp;
        float* spp = (float*)&sp;
        #pragma unroll
        for (int c = 0; c < 4; ++c) {
            float pre = acc_tot[t][c] + bb[c];
            memb[c] += pre;                          // VTHR = 1.0 (exact)
            float s = (memb[c] > 1.0f) ? 1.0f : 0.0f;
            memb[c] *= (1.0f - s);                   // reset to zero
            spp[c] = s;
        }
        *(float4*)(out + ((size_t)t * B + bg) * OUT + o0) = sp;
    }
}

extern "C" void kernel_launch(void* const* d_in, const int* in_sizes, int n_in,
                              void* d_out, int out_size, void* d_ws, size_t ws_size,
                              hipStream_t stream)
{
    const float* x    = (const float*)d_in[0];
    const float* w    = (const float*)d_in[1];
    const float* bias = (const float*)d_in[2];
    float* out = (float*)d_out;

    const int OUT = in_sizes[2];            // 4096
    const int IN  = in_sizes[1] / OUT;      // 4096
    const int BT  = in_sizes[0] / IN;       // 2048
    const int B   = BT / TSTEPS;            // 256

    dim3 grid(OUT / TILE_N, BT / TILE_M);   // (32, 32)
    spike_linear_f32seq<<<grid, 256, 0, stream>>>(x, w, bias, out, B, IN, OUT);
}